// Round 5
// baseline (1153.190 us; speedup 1.0000x reference)
//
#include <hip/hip_runtime.h>
#include <stdint.h>

// CRF log-likelihood. B=256, L=1024, D=126, T=128.
// Kernel 1 (recursion): 16 blocks x 256 threads (4 waves); each block owns 16
// batches (columns). Per step: S[128x16] = Texp[128x128] . E[128x16] via
// mfma_f32_16x16x32_bf16 (4 waves x 2 j-tiles x 4 K-chunks), then
// E_new = S * P * R per column. Texp = 2^(trans*log2e) constant in A-frags.
// P = 2^(x*log2e) staged global->LDS as bf16, 2 chunks (16 steps) deep.
// Per-column rebase R = 2^-(ilogb(colmax)), colmax 2 steps STALE via mod-3
// LDS slots (off the serial chain); exact integer shift bookkeeping (Mint).
// Per-column freeze at l >= len[col] via register-held previous E + cndmask.
// One barrier per step. Kernel 2 adds the (embarrassingly parallel) score.

#define LOG2E 1.4426950408889634f
#define LN2   0.6931471805599453f

constexpr int Bc = 256, Lc = 1024, Dc = 126, Tc = 128;
constexpr int NB  = 16;          // batches (columns) per block
constexpr int CH  = 8;           // steps per staging chunk
constexpr int CHF = CH * Dc;     // 1008 floats per chunk per batch
constexpr int NCH = Lc / CH;     // 128 chunks
constexpr int LROW = 1016;       // Lbuf row length (bf16) per batch
constexpr int EROW = 136;        // E row length (bf16) per batch (pad 128->136)

#if __has_builtin(__builtin_amdgcn_exp2f)
#define FEXP2(x) __builtin_amdgcn_exp2f(x)
#else
#define FEXP2(x) exp2f(x)
#endif
#if __has_builtin(__builtin_amdgcn_logf)
#define FLOG2(x) __builtin_amdgcn_logf(x)
#else
#define FLOG2(x) log2f(x)
#endif

typedef __attribute__((ext_vector_type(8))) short short8;  // 8 bf16 (4 VGPRs)
typedef __attribute__((ext_vector_type(4))) float f32x4;

union U8 { uint32_t u[4]; short8 v; };

// pack two fp32 into one u32 of bf16 (truncation): [hi.bf16 | lo.bf16]
static __device__ __forceinline__ uint32_t pkbf(float hi, float lo) {
    return __builtin_amdgcn_perm(__float_as_uint(hi), __float_as_uint(lo), 0x07060302u);
}

__global__ __launch_bounds__(256, 1) void crf_fwd(
    const float* __restrict__ x,      // [B, L, D]
    const float* __restrict__ trans,  // [T, T]
    const int*   __restrict__ x_len,  // [B]
    float*       __restrict__ out)    // [B]  (writes -partition)
{
    __shared__ unsigned short Elds[2][NB][EROW];   // E bf16, [n][k], dbuf
    __shared__ unsigned short Lb[2][NB][LROW];     // P bf16, [n][sub*126+j], dbuf
    __shared__ float Mx[3][16][4];                 // stale col-max, mod-3 slots
    __shared__ float Tstop[Tc];                    // 2^(trans[127][k]*log2e)
    __shared__ float red[NB][16];                  // partition partials

    const int tid = threadIdx.x;
    const int w   = tid >> 6;        // wave 0..3  -> j-tiles 2w, 2w+1
    const int l6  = tid & 63;
    const int q   = l6 >> 4;         // quad 0..3
    const int n   = l6 & 15;         // column (batch within block)
    const int bb  = tid >> 4;        // staging: batch row 0..15
    const int i   = tid & 15;        // staging: float4 phase 0..15
    const int nb0 = blockIdx.x * NB;

    // D-rows this lane produces: j = j0[t] + reg, j0[t] = 32w + 16t + 4q
    const int j0t0 = 32 * w + 4 * q;
    const int j0t1 = j0t0 + 16;
    const bool m124_0 = (j0t0 == 124);
    const bool m124_1 = (j0t1 == 124);
    const int lenn = x_len[nb0 + n];

    // ---- constant A-frags: Texp[j][k] bf16, A[m=lane&15][k=quad*8+i] ----
    short8 A8[2][4];
#pragma unroll
    for (int t = 0; t < 2; ++t) {
        const int ja = (2 * w + t) * 16 + n;     // A-row uses lane&15
        const float* tr = trans + ja * Tc;
#pragma unroll
        for (int kc = 0; kc < 4; ++kc) {
            float4 u = *reinterpret_cast<const float4*>(tr + kc * 32 + q * 8);
            float4 v = *reinterpret_cast<const float4*>(tr + kc * 32 + q * 8 + 4);
            U8 a;
            a.u[0] = pkbf(FEXP2(u.y * LOG2E), FEXP2(u.x * LOG2E));
            a.u[1] = pkbf(FEXP2(u.w * LOG2E), FEXP2(u.z * LOG2E));
            a.u[2] = pkbf(FEXP2(v.y * LOG2E), FEXP2(v.x * LOG2E));
            a.u[3] = pkbf(FEXP2(v.w * LOG2E), FEXP2(v.z * LOG2E));
            A8[t][kc] = a.v;
        }
    }

    // ---- init E0 = delta(START=126), Tstop, Mx=1.0 ----
    for (int idx = tid; idx < NB * EROW; idx += 256) {
        int k = idx % EROW;
        (&Elds[0][0][0])[idx] = (k == 126) ? (unsigned short)0x3F80 : (unsigned short)0;
    }
    if (tid < Tc) Tstop[tid] = FEXP2(trans[127 * Tc + tid] * LOG2E);
    if (tid < 192) (&Mx[0][0][0])[tid] = 1.0f;

    // previous-E register copy (for frozen columns)
    uint32_t Eplo[2], Ephi[2];
    Eplo[0] = 0u; Ephi[0] = m124_0 ? 0x00003F80u : 0u;
    Eplo[1] = 0u; Ephi[1] = m124_1 ? 0x00003F80u : 0u;

    // ---- staging prologue: chunk 0 -> Lb[0]; chunk 1 into regs ----
    const float* xrow = x + (size_t)(nb0 + bb) * (Lc * Dc);
    float4 stq[16];

#define LOADQ(m, cv) do { if ((m) < 15 || i < 12) \
    stq[m] = *reinterpret_cast<const float4*>(xrow + (cv) * CHF + 4 * (i + 16 * (m))); } while (0)

#define CONVQ(m, dstb) do { if ((m) < 15 || i < 12) { \
    float4 _v = stq[m]; \
    float _e0 = FEXP2(_v.x * LOG2E), _e1 = FEXP2(_v.y * LOG2E); \
    float _e2 = FEXP2(_v.z * LOG2E), _e3 = FEXP2(_v.w * LOG2E); \
    *reinterpret_cast<uint2*>(&Lb[dstb][bb][4 * (i + 16 * (m))]) = \
        make_uint2(pkbf(_e1, _e0), pkbf(_e3, _e2)); } } while (0)

#pragma unroll
    for (int m = 0; m < 16; ++m) LOADQ(m, 0);
#pragma unroll
    for (int m = 0; m < 16; ++m) CONVQ(m, 0);
#pragma unroll
    for (int m = 0; m < 16; ++m) LOADQ(m, 1);

    int Mint = 0;
    int sw = 0, sr = 1;              // Mx write slot l%3, read slot (l+1)%3
    __syncthreads();

    // ---- forward recursion: one barrier per step ----
    for (int l = 0; l < Lc; ++l) {
        const int sub = l & 7;
        const int p   = l & 1;
        const int cb  = (l >> 3) & 1;

        // stale (2-step) column max -> R (off-chain)
        const float4 mx4 = *reinterpret_cast<const float4*>(&Mx[sr][n][0]);
        float cm = fmaxf(fmaxf(mx4.x, mx4.y), fmaxf(mx4.z, mx4.w));
        int   eb = (__float_as_uint(cm) >> 23) & 0xFF;
        float R  = __uint_as_float((uint32_t)(254 - eb) << 23);

        // P for this step (bf16 pairs per tile); mask j>=126 on the 124-tile
        uint32_t pl0, ph0, pl1, ph1;
        {
            int f0 = sub * Dc + j0t0;
            pl0 = *reinterpret_cast<const uint32_t*>(&Lb[cb][n][f0]);
            uint32_t h = *reinterpret_cast<const uint32_t*>(&Lb[cb][n][f0 + 2]);
            ph0 = m124_0 ? 0u : h;
            int f1 = sub * Dc + j0t1;
            pl1 = *reinterpret_cast<const uint32_t*>(&Lb[cb][n][f1]);
            uint32_t h1 = *reinterpret_cast<const uint32_t*>(&Lb[cb][n][f1 + 2]);
            ph1 = m124_1 ? 0u : h1;
        }

        // B-frags from E[p] + MFMA (2 independent 4-deep K chains)
        f32x4 acc0 = {0.f, 0.f, 0.f, 0.f}, acc1 = {0.f, 0.f, 0.f, 0.f};
#pragma unroll
        for (int kc = 0; kc < 4; ++kc) {
            U8 bf;
            *reinterpret_cast<uint4*>(bf.u) =
                *reinterpret_cast<const uint4*>(&Elds[p][n][kc * 32 + q * 8]);
            acc0 = __builtin_amdgcn_mfma_f32_16x16x32_bf16(A8[0][kc], bf.v, acc0, 0, 0, 0);
            acc1 = __builtin_amdgcn_mfma_f32_16x16x32_bf16(A8[1][kc], bf.v, acc1, 0, 0, 0);
        }

        // staging: subs 0-3 convert+write chunk c+1; subs 4-7 load chunk c+2
        if (sub < 4) {
            const int cnext = (l >> 3) + 1;
            if (cnext < NCH) {
                const int db = cnext & 1;
                switch (sub) {
                    case 0:  CONVQ(0, db);  CONVQ(1, db);  CONVQ(2, db);  CONVQ(3, db);  break;
                    case 1:  CONVQ(4, db);  CONVQ(5, db);  CONVQ(6, db);  CONVQ(7, db);  break;
                    case 2:  CONVQ(8, db);  CONVQ(9, db);  CONVQ(10, db); CONVQ(11, db); break;
                    default: CONVQ(12, db); CONVQ(13, db); CONVQ(14, db); CONVQ(15, db); break;
                }
            }
        } else {
            const int c2 = (l >> 3) + 2;
            if (c2 < NCH) {
                switch (sub) {
                    case 4:  LOADQ(0, c2);  LOADQ(1, c2);  LOADQ(2, c2);  LOADQ(3, c2);  break;
                    case 5:  LOADQ(4, c2);  LOADQ(5, c2);  LOADQ(6, c2);  LOADQ(7, c2);  break;
                    case 6:  LOADQ(8, c2);  LOADQ(9, c2);  LOADQ(10, c2); LOADQ(11, c2); break;
                    default: LOADQ(12, c2); LOADQ(13, c2); LOADQ(14, c2); LOADQ(15, c2); break;
                }
            }
        }

        // E_new = S * P * R (freeze frozen columns via register copy)
        const bool av = (l < lenn);
        float mqall = 0.f;
#pragma unroll
        for (int t = 0; t < 2; ++t) {
            f32x4 a = t ? acc1 : acc0;
            uint32_t pl = t ? pl1 : pl0, ph = t ? ph1 : ph0;
            float f0 = __uint_as_float(pl << 16);
            float f1 = __uint_as_float(pl & 0xFFFF0000u);
            float f2 = __uint_as_float(ph << 16);
            float f3 = __uint_as_float(ph & 0xFFFF0000u);
            float e0 = a.x * f0 * R, e1 = a.y * f1 * R;
            float e2 = a.z * f2 * R, e3 = a.w * f3 * R;
            mqall = fmaxf(mqall, fmaxf(fmaxf(e0, e1), fmaxf(e2, e3)));
            uint32_t lo = pkbf(e1, e0), hi = pkbf(e3, e2);
            lo = av ? lo : Eplo[t];
            hi = av ? hi : Ephi[t];
            Eplo[t] = lo; Ephi[t] = hi;
            *reinterpret_cast<uint2*>(&Elds[p ^ 1][n][t ? j0t1 : j0t0]) =
                make_uint2(lo, hi);
        }
        Mint += av ? (eb - 127) : 0;

        // column max for step l+2 (2-stale; cross-quad + cross-wave via LDS)
        float mw = fmaxf(mqall, __shfl_xor(mqall, 16, 64));
        mw = fmaxf(mw, __shfl_xor(mw, 32, 64));
        if (l6 < 16) Mx[sw][l6][w] = mw;

        sw = (sw == 2) ? 0 : sw + 1;
        sr = (sr == 2) ? 0 : sr + 1;
        __syncthreads();
    }

    // ---- partition per column: ln2*(Mint + log2(sum_k Tstop[k]*E[k][n])) ----
    {
        const int part = tid >> 4, n2 = tid & 15;   // final E is in buffer 0
        uint4 ev = *reinterpret_cast<const uint4*>(&Elds[0][n2][part * 8]);
        uint32_t uu[4] = {ev.x, ev.y, ev.z, ev.w};
        const float* ts = &Tstop[part * 8];
        float s = 0.f;
#pragma unroll
        for (int h = 0; h < 4; ++h) {
            s += __uint_as_float(uu[h] << 16)         * ts[2 * h];
            s += __uint_as_float(uu[h] & 0xFFFF0000u) * ts[2 * h + 1];
        }
        red[n2][part] = s;
    }
    __syncthreads();
    if (tid < 16) {
        float S = 0.f;
        const float* rr = &red[tid][0];
#pragma unroll
        for (int h2 = 0; h2 < 16; ++h2) S += rr[h2];
        out[nb0 + tid] = -LN2 * ((float)Mint + FLOG2(S));
    }
#undef LOADQ
#undef CONVQ
}

// Kernel 2: gold score (emission + pairwise transitions), fp32 exact.
__global__ __launch_bounds__(256) void crf_score(
    const float* __restrict__ x, const float* __restrict__ trans,
    const int* __restrict__ x_len, const int* __restrict__ tag,
    float* __restrict__ out)
{
    __shared__ float rs[4];
    const int b = blockIdx.x, tid = threadIdx.x;
    const int len = x_len[b];
    const int*   tb = tag + (size_t)b * Lc;
    const float* xb = x + (size_t)b * Lc * Dc;
    float acc = 0.f;
    for (int l = tid; l < len; l += 256) {
        int tg = tb[l];
        int pv = (l == 0) ? (Tc - 2) : tb[l - 1];
        acc += xb[l * Dc + tg] + trans[tg * Tc + pv];
    }
#pragma unroll
    for (int off = 1; off < 64; off <<= 1)
        acc += __shfl_xor(acc, off, 64);
    if ((tid & 63) == 0) rs[tid >> 6] = acc;
    __syncthreads();
    if (tid == 0) {
        float t = rs[0] + rs[1] + rs[2] + rs[3]
                + trans[(Tc - 1) * Tc + tb[len - 1]];   // STOP transition
        out[b] += t;   // kernel1 already wrote -partition (stream-ordered)
    }
}

extern "C" void kernel_launch(void* const* d_in, const int* in_sizes, int n_in,
                              void* d_out, int out_size, void* d_ws, size_t ws_size,
                              hipStream_t stream) {
    const float* x     = (const float*)d_in[0];
    const float* trans = (const float*)d_in[1];
    // d_in[2] = x_mask (redundant with x_len)
    const int*   x_len = (const int*)d_in[3];
    const int*   tag   = (const int*)d_in[4];
    float*       out   = (float*)d_out;

    crf_fwd<<<Bc / NB, 256, 0, stream>>>(x, trans, x_len, out);
    crf_score<<<Bc, 256, 0, stream>>>(x, trans, x_len, tag, out);
}

// Round 6
// 1042.033 us; speedup vs baseline: 1.1067x; 1.1067x over previous
//
#include <hip/hip_runtime.h>
#include <stdint.h>

// CRF log-likelihood. B=256, L=1024, D=126, T=128.
// Kernel 1: 16 blocks x 512 threads (8 waves, 2/SIMD); block owns 16 batches.
// Per step: S[128x16] = Texp[128x128] . E[128x16] via mfma_f32_16x16x32_bf16
// (wave w owns j-tile [16w,16w+16), one 4-deep K-chain). E'=S*P*R per column.
//   - Raw `s_waitcnt lgkmcnt(0); s_barrier` (CK block_sync_lds idiom): staged
//     global loads stay in flight across barriers (no vmcnt drain).
//   - Closed-loop rebase: exponent of E'[0,n] sampled by wave0/q0, 2-step
//     stale via mod-3 LDS slots; exact integer Mint bookkeeping. No shuffles.
//   - E in LDS [n][64 dw] with 4-dword-block XOR swizzle (reads ~2-way,
//     writes ~2-way). P pre-exponentiated bf16, [sub][jp][n] stride 17.
//   - P staged global->LDS 1 chunk (8 steps) ahead; loads 2 chunks ahead.
// Kernel 2 adds the embarrassingly-parallel gold score.

#define LOG2E 1.4426950408889634f
#define LN2   0.6931471805599453f

constexpr int Bc = 256, Lc = 1024, Dc = 126, Tc = 128;
constexpr int NB   = 16;           // batches per block
constexpr int NBLK = Bc / NB;      // 16 blocks
constexpr int NCH  = Lc / 8;       // 128 chunks of 8 steps

#if __has_builtin(__builtin_amdgcn_exp2f)
#define FEXP2(x) __builtin_amdgcn_exp2f(x)
#else
#define FEXP2(x) exp2f(x)
#endif
#if __has_builtin(__builtin_amdgcn_logf)
#define FLOG2(x) __builtin_amdgcn_logf(x)
#else
#define FLOG2(x) log2f(x)
#endif

typedef __attribute__((ext_vector_type(8))) short short8;  // 8 bf16
typedef __attribute__((ext_vector_type(4))) float f32x4;
union U8 { uint32_t u[4]; short8 v; };

// pack two fp32 -> bf16 pair dword, round-half-up (kills truncation bias)
static __device__ __forceinline__ uint32_t pkrne(float hi, float lo) {
    uint32_t h = __float_as_uint(hi) + 0x8000u;
    uint32_t l = __float_as_uint(lo) + 0x8000u;
    return (h & 0xFFFF0000u) | (l >> 16);
}

// LDS-only barrier: drain lgkm, DO NOT drain vmcnt (global prefetch in flight)
static __device__ __forceinline__ void lds_barrier() {
    asm volatile("s_waitcnt lgkmcnt(0)\ns_barrier" ::: "memory");
}

__global__ __launch_bounds__(512, 1) void crf_fwd(
    const float* __restrict__ x,      // [B, L, D]
    const float* __restrict__ trans,  // [T, T]
    const int*   __restrict__ x_len,  // [B]
    float*       __restrict__ out)    // [B]  (writes -partition)
{
    __shared__ __align__(16) uint32_t Elds[2][NB * 64];     // E bf16 pairs, swizzled
    __shared__ __align__(16) uint32_t Lb[2][8 * 64 * 17];   // P bf16 pairs
    __shared__ int   MxI[3][NB];                            // sampled exponents
    __shared__ float red[NB][36];                           // partition partials

    const int tid = threadIdx.x;
    const int w   = tid >> 6;        // wave 0..7 -> j-tile [16w,16w+16)
    const int l6  = tid & 63;
    const int q   = l6 >> 4;         // MFMA quad
    const int n   = l6 & 15;         // column (batch)
    const int nb0 = blockIdx.x * NB;
    const int lenn = x_len[nb0 + n];

    // ---- A-frags: T row = 16w+n, k = kc*32 + 8q + i;  Texp = 2^(t*log2e) ----
    short8 A8[4];
#pragma unroll
    for (int kc = 0; kc < 4; ++kc) {
        const float* tr = trans + (16 * w + n) * Tc + kc * 32 + 8 * q;
        float4 u = *reinterpret_cast<const float4*>(tr);
        float4 v = *reinterpret_cast<const float4*>(tr + 4);
        U8 a;
        a.u[0] = pkrne(FEXP2(u.y * LOG2E), FEXP2(u.x * LOG2E));
        a.u[1] = pkrne(FEXP2(u.w * LOG2E), FEXP2(u.z * LOG2E));
        a.u[2] = pkrne(FEXP2(v.y * LOG2E), FEXP2(v.x * LOG2E));
        a.u[3] = pkrne(FEXP2(v.w * LOG2E), FEXP2(v.z * LOG2E));
        A8[kc] = a.v;
    }

    // ---- swizzled E addresses (dword idx; blocks of 4 dwords XOR n&7) ----
    int eIdx[4];
#pragma unroll
    for (int kc = 0; kc < 4; ++kc) {
        int blk = 4 * kc + q;
        eIdx[kc] = n * 64 + (((blk ^ (n & 7))) << 2);
    }
    int wIdx;
    { int blkW = 2 * w + (q >> 1);
      wIdx = n * 64 + ((blkW ^ (n & 7)) << 2) + 2 * (q & 1); }
    const int pBase = (8 * w + 2 * q) * 17 + n;   // + sub*1088 in Lb[cb]

    // ---- init LDS: E=delta(row126), Mx slots 1,2 = 127, P rows 126/127 = 0 ----
    for (int idx = tid; idx < 2 * NB * 64; idx += 512) (&Elds[0][0])[idx] = 0u;
    if (tid < 32) MxI[1 + (tid >> 4)][tid & 15] = 127;
    if (tid < 128) {
        int s = (tid >> 4) & 7, nn = tid & 15;
        Lb[0][(s * 64 + 63) * 17 + nn] = 0u;
        Lb[1][(s * 64 + 63) * 17 + nn] = 0u;
    }

    // ---- staging: 32 threads/batch; thread m-th float4: t = i2 + 32m ----
    const int i2 = tid & 31;
    const int sn = tid >> 5;
    const float* xrow = x + (size_t)(nb0 + sn) * (Lc * Dc);
    float4 stq[8];

#define LOADQ(m, cv) do { int _t = i2 + 32 * (m); if (_t < 252) \
    stq[m] = *reinterpret_cast<const float4*>(xrow + (size_t)(cv) * 1008 + 4 * _t); } while (0)
#define CONVQ(m, db) do { int _t = i2 + 32 * (m); if (_t < 252) { \
    int _s = (4 * _t) / 126; int _j = 4 * _t - 126 * _s; \
    float4 _v = stq[m]; \
    uint32_t _d0 = pkrne(FEXP2(_v.y * LOG2E), FEXP2(_v.x * LOG2E)); \
    uint32_t _d1 = pkrne(FEXP2(_v.w * LOG2E), FEXP2(_v.z * LOG2E)); \
    int _i0 = (_s * 64 + (_j >> 1)) * 17 + sn; \
    Lb[db][_i0] = _d0; \
    Lb[db][_i0 + ((_j == 124) ? 34 : 17)] = _d1; } } while (0)

    // prologue: chunk 0 -> Lb[0]; chunk 1 into regs
#pragma unroll
    for (int m = 0; m < 8; ++m) LOADQ(m, 0);
#pragma unroll
    for (int m = 0; m < 8; ++m) CONVQ(m, 0);
#pragma unroll
    for (int m = 0; m < 8; ++m) LOADQ(m, 1);

    // E[0]: row 126 = bf16 1.0 (dw 63, low half), per column
    if (tid < NB) {
        int a = tid * 64 + (((63 >> 2) ^ (tid & 7)) << 2) + 3;
        Elds[0][a] = 0x00003F80u;
    }

    uint32_t loP = 0u, hiP = 0u;     // frozen-register E copy
    int Mint = 0;
    lds_barrier();

    // ---- forward recursion: one LDS-only barrier per step ----
    for (int l = 0; l < Lc; ++l) {
        const int sub = l & 7, p = l & 1, cb = (l >> 3) & 1;

        // rebase factor from 2-step-stale sampled exponent (off-chain)
        int ebR = MxI[(l + 1) % 3][n];
        ebR = (ebR < 40) ? 40 : (ebR > 215 ? 215 : ebR);
        const float R = __uint_as_float((uint32_t)(254 - ebR) << 23);

        // P pair dwords for rows 16w+4q..+3 (issue early)
        const uint32_t pd0 = Lb[cb][pBase + sub * 1088];
        const uint32_t pd1 = Lb[cb][pBase + sub * 1088 + 17];

        // B-frags + 4-deep MFMA K-chain
        const uint32_t* Ep = &Elds[p][0];
        f32x4 acc = {0.f, 0.f, 0.f, 0.f};
#pragma unroll
        for (int kc = 0; kc < 4; ++kc) {
            U8 bf;
            *reinterpret_cast<uint4*>(bf.u) =
                *reinterpret_cast<const uint4*>(&Ep[eIdx[kc]]);
            acc = __builtin_amdgcn_mfma_f32_16x16x32_bf16(A8[kc], bf.v, acc, 0, 0, 0);
        }

        // staging: subs 0-3 convert+write chunk c+1; subs 4-7 load chunk c+2
        if (sub < 4) {
            const int c1 = (l >> 3) + 1;
            if (c1 < NCH) {
                const int db = c1 & 1;
                switch (sub) {
                    case 0:  CONVQ(0, db); CONVQ(1, db); break;
                    case 1:  CONVQ(2, db); CONVQ(3, db); break;
                    case 2:  CONVQ(4, db); CONVQ(5, db); break;
                    default: CONVQ(6, db); CONVQ(7, db); break;
                }
            }
        } else {
            const int c2 = (l >> 3) + 2;
            if (c2 < NCH) {
                switch (sub) {
                    case 4:  LOADQ(0, c2); LOADQ(1, c2); break;
                    case 5:  LOADQ(2, c2); LOADQ(3, c2); break;
                    case 6:  LOADQ(4, c2); LOADQ(5, c2); break;
                    default: LOADQ(6, c2); LOADQ(7, c2); break;
                }
            }
        }

        // epilogue: E' = S * P * R, freeze at l >= len, write next E
        const bool av = (l < lenn);
        float P0 = __uint_as_float(pd0 << 16);
        float P1 = __uint_as_float(pd0 & 0xFFFF0000u);
        float P2 = __uint_as_float(pd1 << 16);
        float P3 = __uint_as_float(pd1 & 0xFFFF0000u);
        float e0 = acc.x * P0 * R, e1 = acc.y * P1 * R;
        float e2 = acc.z * P2 * R, e3 = acc.w * P3 * R;
        uint32_t lo = pkrne(e1, e0), hi = pkrne(e3, e2);
        lo = av ? lo : loP;  hi = av ? hi : hiP;
        loP = lo;  hiP = hi;
        *reinterpret_cast<uint2*>(&Elds[p ^ 1][wIdx]) = make_uint2(lo, hi);

        // sample: wave0/q0 lanes publish exponent of E'[0,n] (bf16 bits 14:7)
        if (tid < 16) MxI[l % 3][n] = (int)((lo >> 7) & 255);
        Mint += av ? (ebR - 127) : 0;

        lds_barrier();
    }

    // ---- partition: per lane, 4 rows of Tstop . E_frozen ----
    {
        const int j0 = 16 * w + 4 * q;
        float4 ts = *reinterpret_cast<const float4*>(trans + 127 * Tc + j0);
        float E0 = __uint_as_float(loP << 16);
        float E1 = __uint_as_float(loP & 0xFFFF0000u);
        float E2 = __uint_as_float(hiP << 16);
        float E3 = __uint_as_float(hiP & 0xFFFF0000u);
        float part = FEXP2(ts.x * LOG2E) * E0 + FEXP2(ts.y * LOG2E) * E1
                   + FEXP2(ts.z * LOG2E) * E2 + FEXP2(ts.w * LOG2E) * E3;
        red[n][4 * w + q] = part;
    }
    __syncthreads();
    if (tid < 16) {
        float S = 0.f;
#pragma unroll
        for (int h = 0; h < 8; ++h) {
            float4 r4 = *reinterpret_cast<const float4*>(&red[tid][4 * h]);
            S += (r4.x + r4.y) + (r4.z + r4.w);
        }
        out[nb0 + tid] = -LN2 * ((float)Mint + FLOG2(S));
    }
#undef LOADQ
#undef CONVQ
}

// Kernel 2: gold score (emission + pairwise transitions), fp32 exact.
__global__ __launch_bounds__(256) void crf_score(
    const float* __restrict__ x, const float* __restrict__ trans,
    const int* __restrict__ x_len, const int* __restrict__ tag,
    float* __restrict__ out)
{
    __shared__ float rs[4];
    const int b = blockIdx.x, tid = threadIdx.x;
    const int len = x_len[b];
    const int*   tb = tag + (size_t)b * Lc;
    const float* xb = x + (size_t)b * Lc * Dc;
    float acc = 0.f;
    for (int l = tid; l < len; l += 256) {
        int tg = tb[l];
        int pv = (l == 0) ? (Tc - 2) : tb[l - 1];
        acc += xb[l * Dc + tg] + trans[tg * Tc + pv];
    }
#pragma unroll
    for (int off = 1; off < 64; off <<= 1)
        acc += __shfl_xor(acc, off, 64);
    if ((tid & 63) == 0) rs[tid >> 6] = acc;
    __syncthreads();
    if (tid == 0) {
        float t = rs[0] + rs[1] + rs[2] + rs[3]
                + trans[(Tc - 1) * Tc + tb[len - 1]];   // STOP transition
        out[b] += t;   // kernel1 already wrote -partition (stream-ordered)
    }
}

extern "C" void kernel_launch(void* const* d_in, const int* in_sizes, int n_in,
                              void* d_out, int out_size, void* d_ws, size_t ws_size,
                              hipStream_t stream) {
    const float* x     = (const float*)d_in[0];
    const float* trans = (const float*)d_in[1];
    // d_in[2] = x_mask (redundant with x_len)
    const int*   x_len = (const int*)d_in[3];
    const int*   tag   = (const int*)d_in[4];
    float*       out   = (float*)d_out;

    crf_fwd<<<NBLK, 512, 0, stream>>>(x, trans, x_len, out);
    crf_score<<<Bc, 256, 0, stream>>>(x, trans, x_len, tag, out);
}

// Round 7
// 876.159 us; speedup vs baseline: 1.3162x; 1.1893x over previous
//
#include <hip/hip_runtime.h>
#include <stdint.h>

// CRF log-likelihood. B=256, L=1024, D=126, T=128.
// Kernel 1: 16 blocks x 256 threads = 4 waves (1/SIMD):
//   wave 0 = consumer: owns 16 batches; holds the ENTIRE Texp=2^(trans*log2e)
//     matrix in A-frags (8 j-tiles x 4 K-chunks, 128 VGPRs). Per step:
//     S[128x16] = Texp . E via 32 mfma_f32_16x16x32_bf16 sharing 4 B-frag
//     ds_read_b128s; E' = S*P*R; E wave-private in LDS -> NO per-step barrier.
//   waves 1-3 = producers: stage x -> exp2 -> packed-bf16 P into LDS in
//     C-frag order (consumer reads P as 4x b128). Sync once per 8 steps.
//   Rebase: R6's proven 2-step-stale closed loop (mod-3 slots), per-column
//   max from 4 per-lane samples read as one b128; exact integer Mint.
// Kernel 2 adds the embarrassingly-parallel gold score.

#define LOG2E 1.4426950408889634f
#define LN2   0.6931471805599453f

constexpr int Bc = 256, Lc = 1024, Dc = 126, Tc = 128;
constexpr int NB   = 16;          // batches per block
constexpr int NBLK = 16;          // blocks
constexpr int NCH  = 128;         // chunks of 8 steps
constexpr int EROW = 68;          // E col stride (dwords): 64 used + 4 pad
constexpr int PROW = 20;          // P row stride (dwords): 16 used + 4 pad
constexpr int PSUB = 64 * PROW;   // dwords per sub-step block (1280)
constexpr int PBUF = 8 * PSUB;    // dwords per chunk buffer (10240)

#if __has_builtin(__builtin_amdgcn_exp2f)
#define FEXP2(x) __builtin_amdgcn_exp2f(x)
#else
#define FEXP2(x) exp2f(x)
#endif
#if __has_builtin(__builtin_amdgcn_logf)
#define FLOG2(x) __builtin_amdgcn_logf(x)
#else
#define FLOG2(x) log2f(x)
#endif

typedef __attribute__((ext_vector_type(8))) short short8;  // 8 bf16
typedef __attribute__((ext_vector_type(4))) float f32x4;
union U8 { uint32_t u[4]; short8 v; };

// pack two fp32 -> bf16 pair dword, round-half-up
static __device__ __forceinline__ uint32_t pkrne(float hi, float lo) {
    uint32_t h = __float_as_uint(hi) + 0x8000u;
    uint32_t l = __float_as_uint(lo) + 0x8000u;
    return (h & 0xFFFF0000u) | (l >> 16);
}
static __device__ __forceinline__ float bflo(uint32_t u) { return __uint_as_float(u << 16); }
static __device__ __forceinline__ float bfhi(uint32_t u) { return __uint_as_float(u & 0xFFFF0000u); }

__global__ __launch_bounds__(256, 1) void crf_fwd(
    const float* __restrict__ x,      // [B, L, D]
    const float* __restrict__ trans,  // [T, T]
    const int*   __restrict__ x_len,  // [B]
    float*       __restrict__ out)    // [B]  (writes -partition)
{
    __shared__ __align__(16) uint32_t Elds[2][NB * EROW];  // E bf16 pairs
    __shared__ __align__(16) uint32_t Pl[2][PBUF];         // P bf16 pairs
    __shared__ __align__(16) int      MxI[3][64];          // per-lane max exps
    __shared__ float red[64];
    __shared__ int   MintS[NB];

    const int tid = threadIdx.x;
    const int w   = tid >> 6;
    const int l6  = tid & 63;
    const int nb0 = blockIdx.x * NB;

    // ---------------- consumer persistent state ----------------
    const int q = l6 >> 4;           // quad
    const int n = l6 & 15;           // column (batch) AND A-row-within-tile
    int      lenn = 1;
    short8   A8[8][4];
    uint32_t Ereg[16];
    int      Mint = 0, sw = 0, sr = 1;
    float    mxKeep = 1.0f;

    // ---------------- producer persistent state ----------------
    int gof[21], lA[21], lB[21];

    if (w == 0) {
        lenn = x_len[nb0 + n];
        // A-frags: A[m=l6&15][k=8q+i] ; row j = 16t + m
#pragma unroll
        for (int t = 0; t < 8; ++t) {
#pragma unroll
            for (int kc = 0; kc < 4; ++kc) {
                const float* tr = trans + (16 * t + n) * Tc + kc * 32 + 8 * q;
                float4 u = *reinterpret_cast<const float4*>(tr);
                float4 v = *reinterpret_cast<const float4*>(tr + 4);
                U8 a;
                a.u[0] = pkrne(FEXP2(u.y * LOG2E), FEXP2(u.x * LOG2E));
                a.u[1] = pkrne(FEXP2(u.w * LOG2E), FEXP2(u.z * LOG2E));
                a.u[2] = pkrne(FEXP2(v.y * LOG2E), FEXP2(v.x * LOG2E));
                a.u[3] = pkrne(FEXP2(v.w * LOG2E), FEXP2(v.z * LOG2E));
                A8[t][kc] = a.v;
            }
        }
        // init E buffers (zero both, then delta at k=126 in buf 0)
        for (int idx = l6; idx < 2 * NB * EROW; idx += 64) (&Elds[0][0])[idx] = 0u;
        // init stale-max slots 1,2 to exponent 127 (R=1)
        for (int idx = l6; idx < 128; idx += 64) MxI[1 + (idx >> 6)][idx & 63] = 127;
        // zero the never-written P dwords (rows 4n+3, d=15: j pair 126/127)
        for (int idx = l6; idx < 256; idx += 64) {
            int buf = idx >> 7, r = idx & 127, sb = r >> 4, nn = r & 15;
            Pl[buf][sb * PSUB + (4 * nn + 3) * PROW + 15] = 0u;
        }
#pragma unroll
        for (int t = 0; t < 16; ++t) Ereg[t] = 0u;
    } else {
        // producers: 192 lanes; 4032 float4s per chunk; 21 each
        const int pid = tid - 64;
#pragma unroll
        for (int i = 0; i < 21; ++i) {
            int idx = i * 192 + pid;          // float4 index in chunk
            int f   = 4 * idx;                // float offset in chunk
            int nn  = f / 1008;
            int rem = f - 1008 * nn;
            int sb  = rem / 126;
            int jj  = rem - 126 * sb;         // even, <= 124
            int j2 = jj + 2, sb2 = sb;
            if (j2 >= 126) { j2 -= 126; sb2 += 1; }
            gof[i] = nn * (Lc * Dc) + rem;
            lA[i] = sb  * PSUB + (4 * nn + ((jj >> 2) & 3)) * PROW + 2 * (jj >> 4) + ((jj >> 1) & 1);
            lB[i] = sb2 * PSUB + (4 * nn + ((j2 >> 2) & 3)) * PROW + 2 * (j2 >> 4) + ((j2 >> 1) & 1);
        }
    }

    const float* xg = x + (size_t)nb0 * (Lc * Dc);
    auto produce = [&](int db, int cc) {
        const int co = cc * 1008;
        float4 pv[21];
#pragma unroll
        for (int i = 0; i < 21; ++i)
            pv[i] = *reinterpret_cast<const float4*>(xg + gof[i] + co);
#pragma unroll
        for (int i = 0; i < 21; ++i) {
            float4 v = pv[i];
            float e0 = FEXP2(v.x * LOG2E), e1 = FEXP2(v.y * LOG2E);
            float e2 = FEXP2(v.z * LOG2E), e3 = FEXP2(v.w * LOG2E);
            Pl[db][lA[i]] = pkrne(e1, e0);
            Pl[db][lB[i]] = pkrne(e3, e2);
        }
    };

    if (w == 0) {
        if (l6 < 16) Elds[0][l6 * EROW + 63] = 0x00003F80u;   // E0 = delta(126)
    } else {
        produce(0, 0);                                        // chunk 0
    }
    __syncthreads();

    // ================= main loop: 128 chunks of 8 steps =================
#pragma unroll 1
    for (int c = 0; c < NCH; ++c) {
        if (w == 0) {
#pragma unroll 2
            for (int sub = 0; sub < 8; ++sub) {
                const int l = 8 * c + sub;
                const int p = l & 1;

                // stale column max (2 steps old) -> uniform-per-column R
                int4 m4 = *reinterpret_cast<const int4*>(&MxI[sr][4 * n]);
                int ebR = max(max(m4.x, m4.y), max(m4.z, m4.w));
                ebR = min(max(ebR, 40), 215);
                const float R = __uint_as_float((uint32_t)(254 - ebR) << 23);

                // P dwords (C-frag order): 4x b128
                const uint32_t* Pb = &Pl[c & 1][sub * PSUB + (4 * n + q) * PROW];
                uint4 pf0 = *reinterpret_cast<const uint4*>(Pb);
                uint4 pf1 = *reinterpret_cast<const uint4*>(Pb + 4);
                uint4 pf2 = *reinterpret_cast<const uint4*>(Pb + 8);
                uint4 pf3 = *reinterpret_cast<const uint4*>(Pb + 12);
                uint32_t pda[16] = {pf0.x, pf0.y, pf0.z, pf0.w,
                                    pf1.x, pf1.y, pf1.z, pf1.w,
                                    pf2.x, pf2.y, pf2.z, pf2.w,
                                    pf3.x, pf3.y, pf3.z, pf3.w};

                // B-frags (shared by all 8 tiles) + 32 MFMA
                U8 bf[4];
#pragma unroll
                for (int kc = 0; kc < 4; ++kc)
                    *reinterpret_cast<uint4*>(bf[kc].u) =
                        *reinterpret_cast<const uint4*>(&Elds[p][n * EROW + kc * 16 + 4 * q]);
                f32x4 acc[8];
#pragma unroll
                for (int t = 0; t < 8; ++t) {
                    acc[t] = (f32x4){0.f, 0.f, 0.f, 0.f};
#pragma unroll
                    for (int kc = 0; kc < 4; ++kc)
                        acc[t] = __builtin_amdgcn_mfma_f32_16x16x32_bf16(
                            A8[t][kc], bf[kc].v, acc[t], 0, 0, 0);
                }

                // epilogue: E' = S*P*R; freeze at l >= len; write + sample
                const bool av = (l < lenn);
                float mxN = 0.f;
#pragma unroll
                for (int t = 0; t < 8; ++t) {
                    uint32_t u0 = pda[2 * t], u1 = pda[2 * t + 1];
                    float e0 = acc[t].x * bflo(u0) * R;
                    float e1 = acc[t].y * bfhi(u0) * R;
                    float e2 = acc[t].z * bflo(u1) * R;
                    float e3 = acc[t].w * bfhi(u1) * R;
                    mxN = fmaxf(mxN, fmaxf(fmaxf(e0, e1), fmaxf(e2, e3)));
                    uint32_t d0 = pkrne(e1, e0), d1 = pkrne(e3, e2);
                    d0 = av ? d0 : Ereg[2 * t];
                    d1 = av ? d1 : Ereg[2 * t + 1];
                    Ereg[2 * t] = d0; Ereg[2 * t + 1] = d1;
                    *reinterpret_cast<uint2*>(&Elds[p ^ 1][n * EROW + 8 * t + 2 * q]) =
                        make_uint2(d0, d1);
                }
                Mint += av ? (ebR - 127) : 0;
                mxKeep = av ? mxN : mxKeep;
                MxI[sw][4 * n + q] = (int)((__float_as_uint(mxKeep) >> 23) & 255);
                sw = (sw == 2) ? 0 : sw + 1;
                sr = (sr == 2) ? 0 : sr + 1;
            }
        } else if (c + 1 < NCH) {
            produce((c + 1) & 1, c + 1);
        }
        __syncthreads();
    }

    // ---- partition per column from frozen Ereg ----
    if (w == 0) {
        float part = 0.f;
#pragma unroll
        for (int t = 0; t < 8; ++t) {
            const float* ts = trans + 127 * Tc + 16 * t + 4 * q;
            float4 t4 = *reinterpret_cast<const float4*>(ts);
            part += FEXP2(t4.x * LOG2E) * bflo(Ereg[2 * t])
                  + FEXP2(t4.y * LOG2E) * bfhi(Ereg[2 * t])
                  + FEXP2(t4.z * LOG2E) * bflo(Ereg[2 * t + 1])
                  + FEXP2(t4.w * LOG2E) * bfhi(Ereg[2 * t + 1]);
        }
        red[4 * n + q] = part;
        if (q == 0) MintS[n] = Mint;
    }
    __syncthreads();
    if (tid < NB) {
        float S = red[4 * tid] + red[4 * tid + 1] + red[4 * tid + 2] + red[4 * tid + 3];
        out[nb0 + tid] = -LN2 * ((float)MintS[tid] + FLOG2(S));
    }
}

// Kernel 2: gold score (emission + pairwise transitions), fp32 exact.
__global__ __launch_bounds__(256) void crf_score(
    const float* __restrict__ x, const float* __restrict__ trans,
    const int* __restrict__ x_len, const int* __restrict__ tag,
    float* __restrict__ out)
{
    __shared__ float rs[4];
    const int b = blockIdx.x, tid = threadIdx.x;
    const int len = x_len[b];
    const int*   tb = tag + (size_t)b * Lc;
    const float* xb = x + (size_t)b * Lc * Dc;
    float acc = 0.f;
    for (int l = tid; l < len; l += 256) {
        int tg = tb[l];
        int pv = (l == 0) ? (Tc - 2) : tb[l - 1];
        acc += xb[l * Dc + tg] + trans[tg * Tc + pv];
    }
#pragma unroll
    for (int off = 1; off < 64; off <<= 1)
        acc += __shfl_xor(acc, off, 64);
    if ((tid & 63) == 0) rs[tid >> 6] = acc;
    __syncthreads();
    if (tid == 0) {
        float t = rs[0] + rs[1] + rs[2] + rs[3]
                + trans[(Tc - 1) * Tc + tb[len - 1]];   // STOP transition
        out[b] += t;   // kernel1 already wrote -partition (stream-ordered)
    }
}

extern "C" void kernel_launch(void* const* d_in, const int* in_sizes, int n_in,
                              void* d_out, int out_size, void* d_ws, size_t ws_size,
                              hipStream_t stream) {
    const float* x     = (const float*)d_in[0];
    const float* trans = (const float*)d_in[1];
    // d_in[2] = x_mask (redundant with x_len)
    const int*   x_len = (const int*)d_in[3];
    const int*   tag   = (const int*)d_in[4];
    float*       out   = (float*)d_out;

    crf_fwd<<<NBLK, 256, 0, stream>>>(x, trans, x_len, out);
    crf_score<<<Bc, 256, 0, stream>>>(x, trans, x_len, tag, out);
}